// Round 1
// baseline (323.222 us; speedup 1.0000x reference)
//
#include <hip/hip_runtime.h>

#define Hh 160
#define Ww 160
#define Cc 64
#define HWc 25600
#define Bb 4

typedef __attribute__((ext_vector_type(8))) short short8;
typedef __attribute__((ext_vector_type(4))) float f32x4;

__device__ __forceinline__ unsigned short f2bf(float f) {
  unsigned int u = __float_as_uint(f);
  unsigned int r = u + 0x7FFFu + ((u >> 16) & 1u);
  return (unsigned short)(r >> 16);
}

// ---------------------------------------------------------------------------
// Kernel 1: 1x1 offset conv + per-pixel clamp + soft-tanh -> (py, px) grid
// pypx[(b*9+kk)*HW + pix] = float2(py, px)
// ---------------------------------------------------------------------------
__global__ __launch_bounds__(256) void k_offsets(
    const float* __restrict__ x, const float* __restrict__ off_w,
    const float* __restrict__ off_b, float2* __restrict__ pypx) {
  __shared__ float sw[18 * 64];
  for (int i = threadIdx.x; i < 18 * 64; i += 256) sw[i] = off_w[i];
  __syncthreads();
  int t = blockIdx.x * 256 + threadIdx.x;  // 0..102399
  int b = t / HWc, pix = t % HWc;
  int h = pix / Ww, w = pix % Ww;
  const float* xp = x + b * Cc * HWc + pix;
  float acc[18];
#pragma unroll
  for (int o = 0; o < 18; o++) acc[o] = off_b[o];
  for (int c = 0; c < Cc; c++) {
    float xv = xp[c * HWc];
#pragma unroll
    for (int o = 0; o < 18; o++) acc[o] += xv * sw[o * 64 + c];
  }
  float fh = (float)h, fw = (float)w;
#pragma unroll
  for (int kk = 0; kk < 9; kk++) {
    float oy = fminf(fmaxf(acc[2 * kk], -fh), 160.0f - fh);
    float ox = fminf(fmaxf(acc[2 * kk + 1], -fw), 160.0f - fw);
    if (fabsf(oy) >= 8.0f) oy = 8.0f * tanhf(oy * 0.125f);
    if (fabsf(ox) >= 8.0f) ox = 8.0f * tanhf(ox * 0.125f);
    float py = fh - 1.0f + (float)(kk / 3) + oy;
    float pxv = fw - 1.0f + (float)(kk % 3) + ox;
    pypx[(b * 9 + kk) * HWc + pix] = make_float2(py, pxv);
  }
}

// ---------------------------------------------------------------------------
// Kernel 2: pre-bake weights in MFMA A-fragment order (bf16).
// n in [0,64): folded pm weights (w_m[n]+w_m[n+64]); n in [64,192): w_n[n-64].
// Element (kk, chunk, nt, lane, j2) -> n = nt*16 + (lane&15),
//                                     c = chunk*32 + (lane>>4)*8 + j2.
// ---------------------------------------------------------------------------
__global__ __launch_bounds__(256) void k_wpack(const float* __restrict__ wm,
                                               const float* __restrict__ wn,
                                               unsigned short* __restrict__ bf) {
  int i = blockIdx.x * 256 + threadIdx.x;
  if (i >= 9 * 2 * 12 * 64 * 8) return;
  int j2 = i & 7;
  int lane = (i >> 3) & 63;
  int ntck = i >> 9;       // ck*12 + nt
  int nt = ntck % 12;
  int ck = ntck / 12;      // kk*2 + chunk
  int kk = ck >> 1;
  int chunk = ck & 1;
  int n = nt * 16 + (lane & 15);
  int c = chunk * 32 + (lane >> 4) * 8 + j2;
  float v;
  if (n < 64)
    v = wm[(n * 64 + c) * 9 + kk] + wm[((n + 64) * 64 + c) * 9 + kk];
  else
    v = wn[((n - 64) * 64 + c) * 9 + kk];
  bf[i] = f2bf(v);
}

// ---------------------------------------------------------------------------
// Kernel 3: fused bilinear gather + MFMA GEMM + pade epilogue.
// WG = 64 pixels (one b, contiguous pix). 4 waves; wave w owns n-tiles
// {w, 4+w, 8+w} (pm, qn0, qn1 for oc in [16w,16w+16)).
// D = A(weights) x B(samples): D row = n (quad*4+r), D col = pixel (lane&15)
// -> coalesced 64B output segments.
// ---------------------------------------------------------------------------
__global__ __launch_bounds__(256) void k_main(
    const float* __restrict__ x, const float* __restrict__ w0,
    const float2* __restrict__ pypx, const unsigned short* __restrict__ bfrag,
    float* __restrict__ out) {
  __shared__ unsigned short A[64 * 72];  // [px][c], rows padded 64->72 (144B)
  const int tid = threadIdx.x;
  const int wg = blockIdx.x;       // 1600
  const int b = wg / 400;
  const int pix0 = (wg % 400) * 64;
  const int wv = tid >> 6;
  const int l = tid & 63;
  const int lm = l & 15;
  const int quad = l >> 4;

  const float* xb = x + b * (Cc * HWc);
  const int cb = wv * 16;          // this wave generates c in [cb, cb+16)
  const float2* pp = pypx + (size_t)(b * 9) * HWc + (pix0 + l);

  f32x4 acc[3][4];
  const f32x4 zero = {0.f, 0.f, 0.f, 0.f};
#pragma unroll
  for (int j = 0; j < 3; j++)
#pragma unroll
    for (int pt = 0; pt < 4; pt++) acc[j][pt] = zero;

  for (int kk = 0; kk < 9; kk++) {
    // ---- bilinear gather for this wave's 16 channels at pixel (pix0+l) ----
    float2 P = pp[kk * HWc];
    float py = P.x, pxv = P.y;
    float y0f = floorf(py), x0f = floorf(pxv);
    float wy = py - y0f, wx = pxv - x0f;
    int y0 = (int)y0f, x0 = (int)x0f;
    float vy0 = (y0 >= 0 && y0 < Hh) ? 1.f : 0.f;
    float vy1 = (y0 >= -1 && y0 < Hh - 1) ? 1.f : 0.f;
    float vx0 = (x0 >= 0 && x0 < Ww) ? 1.f : 0.f;
    float vx1 = (x0 >= -1 && x0 < Ww - 1) ? 1.f : 0.f;
    int r0 = min(max(y0, 0), Hh - 1) * Ww;
    int r1 = min(max(y0 + 1, 0), Hh - 1) * Ww;
    int c0 = min(max(x0, 0), Ww - 1);
    int c1 = min(max(x0 + 1, 0), Ww - 1);
    float w00 = (1.f - wy) * (1.f - wx) * vy0 * vx0;
    float w01 = (1.f - wy) * wx * vy0 * vx1;
    float w10 = wy * (1.f - wx) * vy1 * vx0;
    float w11 = wy * wx * vy1 * vx1;
    const float* pbase = xb + cb * HWc;
    int i00 = r0 + c0, i01 = r0 + c1, i10 = r1 + c0, i11 = r1 + c1;
    unsigned int pk[8];
#pragma unroll
    for (int ci = 0; ci < 16; ci += 2) {
      float s0 = pbase[i00 + ci * HWc] * w00 + pbase[i01 + ci * HWc] * w01 +
                 pbase[i10 + ci * HWc] * w10 + pbase[i11 + ci * HWc] * w11;
      float s1 = pbase[i00 + (ci + 1) * HWc] * w00 +
                 pbase[i01 + (ci + 1) * HWc] * w01 +
                 pbase[i10 + (ci + 1) * HWc] * w10 +
                 pbase[i11 + (ci + 1) * HWc] * w11;
      pk[ci >> 1] = (unsigned int)f2bf(s0) | ((unsigned int)f2bf(s1) << 16);
    }
    __syncthreads();  // previous iteration's MFMA reads of A are done
    unsigned int* ap = (unsigned int*)&A[l * 72 + cb];
    ((uint4*)ap)[0] = make_uint4(pk[0], pk[1], pk[2], pk[3]);
    ((uint4*)ap)[1] = make_uint4(pk[4], pk[5], pk[6], pk[7]);
    __syncthreads();  // A tile visible to all waves

    // ---- MFMA: K = 64 (this kk) in 2 chunks of 32 ----
#pragma unroll
    for (int chunk = 0; chunk < 2; chunk++) {
      short8 sfr[4];
#pragma unroll
      for (int pt = 0; pt < 4; pt++)
        sfr[pt] = *(const short8*)&A[(pt * 16 + lm) * 72 + chunk * 32 + quad * 8];
      short8 wfr[3];
#pragma unroll
      for (int j = 0; j < 3; j++) {
        int nt = j * 4 + wv;
        wfr[j] =
            *(const short8*)&bfrag[((size_t)((kk * 2 + chunk) * 12 + nt) * 64 + l) * 8];
      }
#pragma unroll
      for (int j = 0; j < 3; j++)
#pragma unroll
        for (int pt = 0; pt < 4; pt++)
          acc[j][pt] = __builtin_amdgcn_mfma_f32_16x16x32_bf16(
              wfr[j], sfr[pt], acc[j][pt], 0, 0, 0);
    }
  }

  // ---- epilogue: out = (pm + w0) / (1 + |qn0| + |qn1|) ----
  float w0v[4];
#pragma unroll
  for (int r = 0; r < 4; r++) w0v[r] = w0[wv * 16 + quad * 4 + r];
  float* ob = out + (size_t)b * Cc * HWc + pix0;
#pragma unroll
  for (int pt = 0; pt < 4; pt++) {
#pragma unroll
    for (int r = 0; r < 4; r++) {
      int oc = wv * 16 + quad * 4 + r;
      float pm = acc[0][pt][r] + w0v[r];
      float qn = 1.0f + fabsf(acc[1][pt][r]) + fabsf(acc[2][pt][r]);
      ob[oc * HWc + pt * 16 + lm] = pm / qn;
    }
  }
}

extern "C" void kernel_launch(void* const* d_in, const int* in_sizes, int n_in,
                              void* d_out, int out_size, void* d_ws, size_t ws_size,
                              hipStream_t stream) {
  const float* x = (const float*)d_in[0];      // [4,64,160,160]
  const float* off_w = (const float*)d_in[1];  // [18,64]
  const float* off_b = (const float*)d_in[2];  // [18]
  const float* w_m = (const float*)d_in[3];    // [128,64,3,3]
  const float* w_n = (const float*)d_in[4];    // [128,64,3,3]
  const float* w0 = (const float*)d_in[5];     // [64]
  float* out = (float*)d_out;                  // [4,64,160,160]

  float2* pypx = (float2*)d_ws;                                  // 7,372,800 B
  unsigned short* bfrag =
      (unsigned short*)((char*)d_ws + (size_t)Bb * 9 * HWc * 8); // 221,184 B

  hipLaunchKernelGGL(k_offsets, dim3(400), dim3(256), 0, stream, x, off_w,
                     off_b, pypx);
  hipLaunchKernelGGL(k_wpack, dim3(432), dim3(256), 0, stream, w_m, w_n, bfrag);
  hipLaunchKernelGGL(k_main, dim3(1600), dim3(256), 0, stream, x, w0, pypx,
                     bfrag, out);
}